// Round 4
// baseline (634.634 us; speedup 1.0000x reference)
//
#include <hip/hip_runtime.h>

// INT4PackedLinear: y[64,28672] = x[64,8192] @ dequant(w_packed, scales) + bias
// Dtype contract (verified R0-R6): x/scales/bias/y are FLOAT32, w_packed int32.
//
// R8: 4x byte cut -> main only -40us (not HBM-byte-bound). R9: distance-2
// LDS-DMA ring -> exactly null. Conclusion: every phase all waves park at a
// barrier whose vmcnt transitively waits the w-HBM stream (x and w share one
// in-order VMEM queue); T_phase ~9000cyc vs ~600cyc of work.
// R10: w goes DIRECT TO VGPRS (8 global_load_dword/wave/phase, 3 named reg
// sets, distance 2). Per phase the x-DMA is issued FIRST, w-loads AFTER
// (sched_barrier pins order): the pre-barrier s_waitcnt vmcnt(28) retires
// ONLY x (L2-hot); w is waited only by the compiler's counted vmcnt at the
// register consumer inside compute - the barrier is never chained to HBM.
// Same dequant/MFMA/epilogue numerics as the verified kernel. LDS 28KB
// (3 x-slots + sb), launch_bounds(256,4).

typedef short  short8  __attribute__((ext_vector_type(8)));
typedef float  float4v __attribute__((ext_vector_type(4)));
typedef int    int4v   __attribute__((ext_vector_type(4)));
typedef unsigned int uint4v __attribute__((ext_vector_type(4)));

constexpr int Kd = 8192;
constexpr int Nd = 28672;
constexpr int KSPLIT = 4;           // 4 k-partitions of 2048

__device__ __forceinline__ unsigned f32_to_bf16_rn(float f) {
    unsigned u = __builtin_bit_cast(unsigned, f);
    return (u + 0x7FFFu + ((u >> 16) & 1u)) >> 16;
}

// async global->LDS DMA: 16B per lane at (wave-uniform base) + lane*16B.
__device__ __forceinline__ void async16(const void* g, void* l) {
    __builtin_amdgcn_global_load_lds(
        (const __attribute__((address_space(1))) unsigned*)g,
        (__attribute__((address_space(3))) unsigned*)l, 16, 0, 0);
}

// ---- y := bias broadcast over 64 rows ----
__global__ __launch_bounds__(256)
void init_y_kernel(const float* __restrict__ bias, float* __restrict__ y) {
    const int gid = blockIdx.x * 256 + threadIdx.x;       // 458752 = 64*7168
    const int m  = gid / (Nd / 4);
    const int nq = gid % (Nd / 4);
    ((float4v*)y)[(long)m * (Nd / 4) + nq] = ((const float4v*)bias)[nq];
}

// ---- x f32 -> bf16 into workspace ----
__global__ __launch_bounds__(256)
void cvt_x_kernel(const float* __restrict__ x, unsigned short* __restrict__ o) {
    const int i = (blockIdx.x * 256 + threadIdx.x) * 8;
    float4v a = *(const float4v*)(x + i);
    float4v b = *(const float4v*)(x + i + 4);
    union { unsigned short s[8]; short8 v; } r;
    #pragma unroll
    for (int j = 0; j < 4; ++j) {
        r.s[j]     = (unsigned short)f32_to_bf16_rn(a[j]);
        r.s[4 + j] = (unsigned short)f32_to_bf16_rn(b[j]);
    }
    *(short8*)(o + i) = r.v;
}

// ---- main: grid (448, 4), block 256; w->VGPR streaming, x->LDS 3-slot ring ----
__global__ __launch_bounds__(256, 4)
void int4_main_kernel(const unsigned short* __restrict__ xw,
                      const int*            __restrict__ wp,
                      const float*          __restrict__ scales,
                      float*                __restrict__ y)
{
    __shared__ unsigned xbA[2048], xbB[2048], xbC[2048]; // x half-group: 64m x 8 ch
    __shared__ unsigned sb[1024];                        // scales: 16 g x 64 n (f32)

    const int t = threadIdx.x, lane = t & 63, wv = t >> 6;
    const int q = lane >> 4, c = lane & 15;
    const int n0 = blockIdx.x * 64, kz = blockIdx.y;

    // ---- w: per-lane direct loads. Lane (q,c,wv) owns col n0+wv*16+c; per
    // phase p it loads rows kz*1024 + p*32 + it*16 + q*4 + i  (it=0,1; i=0..3),
    // i.e. exactly the dwords the verified LDS path delivered to this lane.
    const int* wbase = wp + (long)(kz * 1024 + q * 4) * Nd + n0 + wv * 16 + c;

    // x instr i: s = wv*128 + i*64 + lane ; m = s>>3 ; kq = (s&7)^(m&7)
    const unsigned short* xsrc0; const unsigned short* xsrc1;
    {
        int s0 = wv * 128 + 0 * 64 + lane, m0 = s0 >> 3, k0 = (s0 & 7) ^ (m0 & 7);
        int s1 = wv * 128 + 1 * 64 + lane, m1 = s1 >> 3, k1 = (s1 & 7) ^ (m1 & 7);
        xsrc0 = xw + (long)m0 * Kd + kz * 2048 + k0 * 8;
        xsrc1 = xw + (long)m1 * Kd + kz * 2048 + k1 * 8;
    }
    const int ldof = wv * 512;   // dwords; instr1 adds +256

    auto stagex = [&](int hg, unsigned* xbuf) {
        const long xof = (long)hg * 64;         // 64 k elems per half-group
        async16(xsrc0 + xof, xbuf + ldof);
        async16(xsrc1 + xof, xbuf + ldof + 256);
    };
    auto loadw = [&](int ph, unsigned (&r)[8]) {
        const int* b = wbase + (long)ph * 32 * Nd;
        #pragma unroll
        for (int it = 0; it < 2; ++it)
            #pragma unroll
            for (int i = 0; i < 4; ++i)
                r[it * 4 + i] = (unsigned)b[(long)(it * 16 + i) * Nd];
    };

    float4v acc[4] = {};

    auto compute = [&](const unsigned* xbuf, const unsigned (&wr)[8], int g) {
        const float s   = __builtin_bit_cast(float, sb[g * 64 + wv * 16 + c]);
        const float m8s = -8.0f * s;
        #pragma unroll
        for (int it = 0; it < 2; ++it) {
            union { short8 h; unsigned u[4]; } bu;
            #pragma unroll
            for (int i = 0; i < 4; ++i) {
                unsigned v = wr[it * 4 + i];
                float lo = fmaf((float)(v & 15u), s, m8s);          // ==((v&15)-8)*s
                float hi = fmaf((float)((v >> 4) & 15u), s, m8s);
                bu.u[i] = f32_to_bf16_rn(lo) | (f32_to_bf16_rn(hi) << 16);
            }
            __builtin_amdgcn_s_setprio(1);
            #pragma unroll
            for (int mt = 0; mt < 4; ++mt) {
                int m = mt * 16 + c;
                int slot = m * 8 + ((it * 4 + q) ^ (c & 7));        // XOR-swizzled
                short8 a = *(const short8*)(xbuf + slot * 4);
                acc[mt] = __builtin_amdgcn_mfma_f32_16x16x32_bf16(a, bu.h, acc[mt], 0, 0, 0);
            }
            __builtin_amdgcn_s_setprio(0);
        }
    };

    unsigned wr0[8], wr1[8], wr2[8];

    // ---- prologue: scales DMA (1) + x(0),w(0) + x(1),w(1).  Queue (old->new):
    // sb,x0(2),w0(8),x1(2),w1(8) = 21 outstanding.
    {
        const float* ssrc = scales + (long)(kz * 16 + (t >> 4)) * Nd + n0 + (t & 15) * 4;
        async16(ssrc, sb + wv * 256);
    }
    stagex(0, xbA);
    __builtin_amdgcn_sched_barrier(0);   // pin: x-DMA issues before w-loads
    loadw(0, wr0);
    __builtin_amdgcn_sched_barrier(0);
    stagex(1, xbB);
    __builtin_amdgcn_sched_barrier(0);
    loadw(1, wr1);
    __builtin_amdgcn_sched_barrier(0);

    // ---- main loop. Steady state before the wait (old->new):
    //   [x(p):2] w(p):8 x(p+1):2 w(p+1):8 x(p+2):2 w(p+2):8  -> 30 outstanding.
    // vmcnt(28) retires ONLY x(p) (plus sb at p=0). w(p) is retired by the
    // compiler's counted wait at its register use inside compute - never at
    // the barrier.
    for (int g3 = 0; g3 < 10; ++g3) {
        const int p = 3 * g3;
        stagex(p + 2, xbC);
        __builtin_amdgcn_sched_barrier(0);
        loadw(p + 2, wr2);
        asm volatile("s_waitcnt vmcnt(28)\ns_barrier" ::: "memory");
        compute(xbA, wr0, p >> 1);
        asm volatile("s_waitcnt lgkmcnt(0)\ns_barrier" ::: "memory");

        stagex(p + 3, xbA);
        __builtin_amdgcn_sched_barrier(0);
        loadw(p + 3, wr0);
        asm volatile("s_waitcnt vmcnt(28)\ns_barrier" ::: "memory");
        compute(xbB, wr1, (p + 1) >> 1);
        asm volatile("s_waitcnt lgkmcnt(0)\ns_barrier" ::: "memory");

        stagex(p + 4, xbB);
        __builtin_amdgcn_sched_barrier(0);
        loadw(p + 4, wr1);
        asm volatile("s_waitcnt vmcnt(28)\ns_barrier" ::: "memory");
        compute(xbC, wr2, (p + 2) >> 1);
        asm volatile("s_waitcnt lgkmcnt(0)\ns_barrier" ::: "memory");
    }
    // tail: phases 30 (xbA/wr0), 31 (xbB/wr1).
    // outstanding: x30:2 w30:8 x31:2 w31:8 = 20 -> retire x30: vmcnt(18)
    asm volatile("s_waitcnt vmcnt(18)\ns_barrier" ::: "memory");
    compute(xbA, wr0, 15);
    asm volatile("s_waitcnt lgkmcnt(0)\ns_barrier" ::: "memory");
    // outstanding: x31:2 w31:8 = 10 -> retire x31: vmcnt(8)
    asm volatile("s_waitcnt vmcnt(8)\ns_barrier" ::: "memory");
    compute(xbB, wr1, 15);

    // ---- epilogue: C/D row m = mt*16 + q*4 + r, col n = n0 + wv*16 + c ----
    const int nw = n0 + wv * 16 + c;
    #pragma unroll
    for (int mt = 0; mt < 4; ++mt)
        #pragma unroll
        for (int r = 0; r < 4; ++r)
            atomicAdd(&y[(long)(mt * 16 + q * 4 + r) * Nd + nw], acc[mt][r]);
}

// ---- fallback main (no ws): R4 structure, inline f32->bf16 A loads ----
__global__ __launch_bounds__(256, 6)
void int4_main_nows_kernel(const float* __restrict__ xf,
                           const int*   __restrict__ wp,
                           const float* __restrict__ scales,
                           float*       __restrict__ y)
{
    constexpr int LDS_STRIDE = 68;
    __shared__ unsigned lds_w[64 * LDS_STRIDE];
    const int t = threadIdx.x, lane = t & 63, wv = t >> 6;
    const int q = lane >> 4, c = lane & 15;
    const int n0 = blockIdx.x * 64, kz = blockIdx.y;
    const int sr = t >> 4, ss = t & 15;
    const int*   wp_b = wp + (long)(kz * 1024 + sr) * Nd + n0 + 4 * ss;
    const float* sc_b = scales + (long)(kz * 16) * Nd + n0 + 4 * ss;
    const float* xf_b = xf + (long)c * Kd + kz * 2048 + q * 8;
    float4v acc[4] = {};

    for (int g = 0; g < 16; ++g) {
        const float4v s4 = *(const float4v*)(sc_b + (long)g * Nd);
        const int* wg = wp_b + (long)g * 64 * Nd;
        #pragma unroll
        for (int i = 0; i < 4; ++i) {
            int4v v = *(const int4v*)(wg + (long)i * 16 * Nd);
            uint4v pk;
            #pragma unroll
            for (int j = 0; j < 4; ++j) {
                float lo = (float)((v[j] & 15) - 8) * s4[j];
                float hi = (float)(((v[j] >> 4) & 15) - 8) * s4[j];
                pk[j] = f32_to_bf16_rn(lo) | (f32_to_bf16_rn(hi) << 16);
            }
            *(uint4v*)&lds_w[(i * 16 + sr) * LDS_STRIDE + 4 * ss] = pk;
        }
        __syncthreads();
        const float* xg = xf_b + g * 128;
        #pragma unroll
        for (int it = 0; it < 4; ++it) {
            union { short8 h; unsigned u[4]; } bu;
            #pragma unroll
            for (int i = 0; i < 4; ++i)
                bu.u[i] = lds_w[(it * 16 + q * 4 + i) * LDS_STRIDE + wv * 16 + c];
            const short8 b = bu.h;
            const float* xk = xg + it * 32;
            #pragma unroll
            for (int mt = 0; mt < 4; ++mt) {
                float4v a0 = *(const float4v*)(xk + (long)mt * 16 * Kd);
                float4v a1 = *(const float4v*)(xk + (long)mt * 16 * Kd + 4);
                union { unsigned short s[8]; short8 v; } r;
                #pragma unroll
                for (int j = 0; j < 4; ++j) {
                    r.s[j]     = (unsigned short)f32_to_bf16_rn(a0[j]);
                    r.s[4 + j] = (unsigned short)f32_to_bf16_rn(a1[j]);
                }
                acc[mt] = __builtin_amdgcn_mfma_f32_16x16x32_bf16(r.v, b, acc[mt], 0, 0, 0);
            }
        }
        __syncthreads();
    }
    const int nw = n0 + wv * 16 + c;
    #pragma unroll
    for (int mt = 0; mt < 4; ++mt)
        #pragma unroll
        for (int r = 0; r < 4; ++r)
            atomicAdd(&y[(long)(mt * 16 + q * 4 + r) * Nd + nw], acc[mt][r]);
}

extern "C" void kernel_launch(void* const* d_in, const int* in_sizes, int n_in,
                              void* d_out, int out_size, void* d_ws, size_t ws_size,
                              hipStream_t stream) {
    const float* x      = (const float*)d_in[0];
    const int*   wp     = (const int*)d_in[1];
    const float* scales = (const float*)d_in[2];
    const float* bias   = (const float*)d_in[3];
    float*       y      = (float*)d_out;

    init_y_kernel<<<dim3(1792), dim3(256), 0, stream>>>(bias, y);

    const size_t xb_bytes = (size_t)64 * Kd * sizeof(unsigned short); // 1 MB
    dim3 grid(Nd / 64, KSPLIT);   // (448, 4) -> 1792 blocks
    dim3 block(256);

    if (ws_size >= xb_bytes) {
        unsigned short* xb = (unsigned short*)d_ws;
        cvt_x_kernel<<<dim3(256), dim3(256), 0, stream>>>(x, xb);
        int4_main_kernel<<<grid, block, 0, stream>>>(xb, wp, scales, y);
    } else {
        int4_main_nows_kernel<<<grid, block, 0, stream>>>(x, wp, scales, y);
    }
}